// Round 24
// baseline (233.074 us; speedup 1.0000x reference)
//
#include <hip/hip_runtime.h>
#include <math.h>

#define BB 8
#define NN 8192
#define CC 64
#define FE 32
#define KN 16
#define CP3 67
#define QPW 4                 // queries per wave (one per cell-rank stratum)
#define WPB 4                 // waves per block
#define CAPQ 64               // per-query stack (count-checked => exact)
#define YB 32
#define ZB 32
#define NCELL (YB * ZB)

// Device-global scratch (module .bss). All bytes written every launch before read.
__device__ double g_part[BB * CC * 2];        // per-(b,c) BN partial sums
__device__ float g_feat0[BB * NN * FE];       // 8 MB
__device__ int   g_idx[BB * NN * KN];         // 4 MB
__device__ float4 g_sorted[BB * NN];          // cell-sorted {x,y,z,xx}
__device__ int    g_sorig[BB * NN];           // sorted -> original index
__device__ unsigned g_binoff[BB * (NCELL + 1)];

// Identical in k_zbin and k_knn (same source => same bits; monotone).
__device__ __forceinline__ int cbin(float v) {
    int bi = (int)((v + 4.5f) * (32.0f / 9.0f));   // 32 bins over [-4.5,4.5]
    if (bi < 0) bi = 0;
    if (bi > 31) bi = 31;
    return bi;
}
// FROZEN reference xx (verified R5, XLA-CPU FMA contraction)
__device__ __forceinline__ float frz_xx(float x, float y, float z) {
    return __fmaf_rn(z, z, __fmaf_rn(y, y, __fmul_rn(x, x)));
}

// ---------------- kernel 1: BN partial sums, one block per (b,c) ----------
__global__ __launch_bounds__(256) void k_bnstats(const float* __restrict__ feat) {
    int bc = blockIdx.x;                        // b*64 + c, 512 blocks
    const float* p = feat + (size_t)bc * NN;    // coalesced single stream
    int tid = threadIdx.x;
    double s = 0.0, s2 = 0.0;
    for (int n = tid; n < NN; n += 256) {
        double v = (double)p[n];
        s += v; s2 += v * v;
    }
    __shared__ double sh[256], sh2[256];
    sh[tid] = s; sh2[tid] = s2;
    __syncthreads();
    for (int off = 128; off > 0; off >>= 1) {
        if (tid < off) { sh[tid] += sh[tid + off]; sh2[tid] += sh2[tid + off]; }
        __syncthreads();
    }
    if (tid == 0) {
        g_part[bc * 2]     = sh[0];
        g_part[bc * 2 + 1] = sh2[0];
    }
}

// ---------------- kernel 1b: (y,z) cell binning -----------------------
__global__ __launch_bounds__(1024) void k_zbin(const float* __restrict__ xyz) {
    __shared__ unsigned hist[NCELL];
    __shared__ unsigned scan[NCELL];
    __shared__ unsigned boff[NCELL + 1];
    int b = blockIdx.x;
    int tid = threadIdx.x;
    hist[tid] = 0;
    __syncthreads();
    const float* bx = xyz + (size_t)b * NN * 3;
    for (int n = tid; n < NN; n += 1024) {
        float y = bx[n * 3 + 1], z = bx[n * 3 + 2];
        atomicAdd(&hist[cbin(y) * ZB + cbin(z)], 1u);
    }
    __syncthreads();
    scan[tid] = hist[tid];
    __syncthreads();
    for (int off = 1; off < NCELL; off <<= 1) {
        unsigned add = (tid >= off) ? scan[tid - off] : 0u;
        __syncthreads();
        scan[tid] += add;
        __syncthreads();
    }
    if (tid == 0) boff[0] = 0;
    boff[tid + 1] = scan[tid];
    __syncthreads();
    hist[tid] = 0;                               // reuse as cursors
    g_binoff[b * (NCELL + 1) + tid + 1] = boff[tid + 1];
    if (tid == 0) g_binoff[b * (NCELL + 1)] = 0;
    __syncthreads();
    for (int n = tid; n < NN; n += 1024) {
        const float* p = bx + (size_t)n * 3;
        float x = p[0], y = p[1], z = p[2];
        int cell = cbin(y) * ZB + cbin(z);
        unsigned pos = boff[cell] + atomicAdd(&hist[cell], 1u);
        g_sorted[(size_t)b * NN + pos] = make_float4(x, y, z, frz_xx(x, y, z));
        g_sorig[(size_t)b * NN + pos] = n;
    }
}

// ---------------- kernel 2: feat0 = Wg' * [feat;xyz] + bias0 ----------------
__global__ __launch_bounds__(256) void k_feat0(const float* __restrict__ feat,
        const float* __restrict__ xyz, const float* __restrict__ Wg,
        const float* __restrict__ gamma, const float* __restrict__ beta) {
    __shared__ float scs[CC], shs[CC];
    __shared__ float wgs[CP3 * FE];
    __shared__ float bias0[FE];
    int tid = threadIdx.x;
    if (tid < CC) {
        double s = 0.0, s2 = 0.0;
        for (int bb2 = 0; bb2 < BB; ++bb2) {
            s  += g_part[((bb2 << 6) + tid) * 2];
            s2 += g_part[((bb2 << 6) + tid) * 2 + 1];
        }
        double inv = 1.0 / (double)(BB * NN);
        double mean = s * inv;
        double var = s2 * inv - mean * mean;
        float sc = gamma[tid] * (float)(1.0 / sqrt(var + (double)1e-5f));
        scs[tid] = sc;
        shs[tid] = beta[tid] - sc * (float)mean;
    }
    __syncthreads();
    for (int i = tid; i < CP3 * FE; i += 256) {
        int c = i >> 5, e = i & 31;
        float w = Wg[e * CP3 + c];
        if (c < CC) w *= scs[c];
        wgs[c * FE + e] = w;
    }
    if (tid < FE) {
        float sacc = 0.f;
        for (int c = 0; c < CC; ++c) sacc = fmaf(Wg[tid * CP3 + c], shs[c], sacc);
        bias0[tid] = sacc;
    }
    __syncthreads();
    int b = blockIdx.x >> 5;
    int n = ((blockIdx.x & 31) << 8) + tid;
    const float* pz = xyz + ((size_t)(b * NN + n)) * 3;
    float x = pz[0], y = pz[1], z = pz[2];

    float acc[FE];
    #pragma unroll
    for (int e = 0; e < FE; ++e) acc[e] = bias0[e];
    const float* fp = feat + (size_t)b * CC * NN + n;
    for (int c = 0; c < CC; ++c) {
        float v = fp[(size_t)c * NN];
        const float4* w4 = (const float4*)(wgs + c * FE);
        #pragma unroll
        for (int e0 = 0; e0 < 8; ++e0) {
            float4 w = w4[e0];
            acc[e0 * 4 + 0] = fmaf(w.x, v, acc[e0 * 4 + 0]);
            acc[e0 * 4 + 1] = fmaf(w.y, v, acc[e0 * 4 + 1]);
            acc[e0 * 4 + 2] = fmaf(w.z, v, acc[e0 * 4 + 2]);
            acc[e0 * 4 + 3] = fmaf(w.w, v, acc[e0 * 4 + 3]);
        }
    }
    #pragma unroll
    for (int d = 0; d < 3; ++d) {
        float v = (d == 0) ? x : ((d == 1) ? y : z);
        const float4* w4 = (const float4*)(wgs + (CC + d) * FE);
        #pragma unroll
        for (int e0 = 0; e0 < 8; ++e0) {
            float4 w = w4[e0];
            acc[e0 * 4 + 0] = fmaf(w.x, v, acc[e0 * 4 + 0]);
            acc[e0 * 4 + 1] = fmaf(w.y, v, acc[e0 * 4 + 1]);
            acc[e0 * 4 + 2] = fmaf(w.z, v, acc[e0 * 4 + 2]);
            acc[e0 * 4 + 3] = fmaf(w.w, v, acc[e0 * 4 + 3]);
        }
    }
    float4* outp = (float4*)(g_feat0 + ((size_t)(b * NN + n)) * FE);
    #pragma unroll
    for (int e0 = 0; e0 < 8; ++e0)
        outp[e0] = make_float4(acc[e0 * 4 + 0], acc[e0 * 4 + 1], acc[e0 * 4 + 2], acc[e0 * 4 + 3]);
}

// ---------------- kernel 3: circle-trimmed 256-chunk stratified KNN -------
// FROZEN reference arithmetic (verified R5):
//   dot  = fma(zq,zm, fma(yq,ym, xq*xm))
//   dist = fadd( fma(-2, dot, xx_q), xx_m )
// R24 = R23 with 4 cands/lane (256-chunk, contiguous 64B/lane = 4
// independent loads/step): typical ~150-cand row segment = ONE chunk, so
// dependent-chain steps/window halve again and ~8 loads stay in flight
// (incl. prefetch). Lane utilization unchanged (ceil-to-chunk). Push order
// permutes -- irrelevant: counting-rank sorts by (dist,idx) key and the
// count-check needs only the exact passer set/count. All other machinery
// byte-identical: circle z-trim + coverage (R23), cell windows (R18),
// gate+count-check [16,64], bracketed bisection (R12), counting-rank (R13),
// SO[] only for passers (R15) => identical neighbor sets.
__global__ __launch_bounds__(256) void k_knn() {
    __shared__ unsigned long long qbuf[WPB * CAPQ];   // 2 KB
    int tid = threadIdx.x;
    int lane = tid & 63;
    int w = tid >> 6;
    int wid = blockIdx.x * WPB + w;             // 0..16383
    int b = wid >> 11;                          // 2048 waves per batch
    int g = wid & 2047;
    const float4* S = g_sorted + (size_t)b * NN;
    const int* SO = g_sorig + (size_t)b * NN;
    const unsigned* BO = g_binoff + b * (NCELL + 1);
    unsigned long long lt = (1ull << lane) - 1ull;
    unsigned long long* pb = qbuf + w * CAPQ;

    #pragma unroll 1
    for (int i = 0; i < QPW; ++i) {
        int qrank = g + (i << 11);              // stratum i sample
        float4 qv = S[qrank];
        float qx = qv.x, qy = qv.y, qz = qv.z, qxx = qv.w;
        int qorig = SO[qrank];
        float tt = 0.053f * __expf(qxx * (1.0f / 3.0f));   // ~32 expected passers
        float t0 = tt > 3.f ? 3.f : tt;
        float tlo = 0.f, thi = 0.f;             // bracket ends (0 = unset)
        unsigned cnt = 0;

        for (int attempt = 0; attempt < 40; ++attempt) {
            cnt = 0;
            float tpe = t0 + 1e-3f;
            float R = __fsqrt_rn(tpe) + 1e-3f;
            int ylo = cbin(qy - R), yhi = cbin(qy + R);

            // enter first nonempty row segment (circle-trimmed z range)
            int yb = ylo, p = 0, hi = 0;
            {
                float rowlo = 0.28125f * (float)yb - 4.5f;
                float dy = fmaxf(0.f, fmaxf(rowlo - qy, qy - (rowlo + 0.28125f)));
                float rz2 = tpe - dy * dy;
                if (rz2 > 0.f) {
                    float Rz = __fsqrt_rn(rz2) + 1e-3f;
                    int zl = cbin(qz - Rz), zh = cbin(qz + Rz);
                    p = (int)BO[yb * ZB + zl]; hi = (int)BO[yb * ZB + zh + 1];
                }
            }
            while (p >= hi && yb < yhi) {
                ++yb;
                float rowlo = 0.28125f * (float)yb - 4.5f;
                float dy = fmaxf(0.f, fmaxf(rowlo - qy, qy - (rowlo + 0.28125f)));
                float rz2 = tpe - dy * dy;
                if (rz2 > 0.f) {
                    float Rz = __fsqrt_rn(rz2) + 1e-3f;
                    int zl = cbin(qz - Rz), zh = cbin(qz + Rz);
                    p = (int)BO[yb * ZB + zl]; hi = (int)BO[yb * ZB + zh + 1];
                } else { p = 0; hi = 0; }
            }
            bool have = p < hi;
            int jc0 = 0, jc1 = 0, jc2 = 0, jc3 = 0;
            bool in0 = false, in1 = false, in2 = false, in3 = false;
            float4 c0, c1, c2, c3;
            if (have) {
                int base = p + 4 * lane;
                jc0 = base < hi ? base : hi - 1;
                jc1 = base + 1 < hi ? base + 1 : hi - 1;
                jc2 = base + 2 < hi ? base + 2 : hi - 1;
                jc3 = base + 3 < hi ? base + 3 : hi - 1;
                c0 = S[jc0]; c1 = S[jc1]; c2 = S[jc2]; c3 = S[jc3];
                in0 = base < hi; in1 = base + 1 < hi;
                in2 = base + 2 < hi; in3 = base + 3 < hi;
            }
            while (have) {
                // advance cursor (uniform) + prefetch next 256-chunk
                int yb2 = yb, p2 = p + 256, hi2 = hi;
                while (p2 >= hi2 && yb2 < yhi) {
                    ++yb2;
                    float rowlo = 0.28125f * (float)yb2 - 4.5f;
                    float dy = fmaxf(0.f, fmaxf(rowlo - qy, qy - (rowlo + 0.28125f)));
                    float rz2 = tpe - dy * dy;
                    if (rz2 > 0.f) {
                        float Rz = __fsqrt_rn(rz2) + 1e-3f;
                        int zl = cbin(qz - Rz), zh = cbin(qz + Rz);
                        p2 = (int)BO[yb2 * ZB + zl]; hi2 = (int)BO[yb2 * ZB + zh + 1];
                    } else { p2 = 0; hi2 = 0; }
                }
                bool have2 = p2 < hi2;
                int jn0 = jc0, jn1 = jc1, jn2 = jc2, jn3 = jc3;
                bool inn0 = false, inn1 = false, inn2 = false, inn3 = false;
                float4 n0 = c0, n1 = c1, n2 = c2, n3 = c3;
                if (have2) {
                    int base = p2 + 4 * lane;
                    jn0 = base < hi2 ? base : hi2 - 1;
                    jn1 = base + 1 < hi2 ? base + 1 : hi2 - 1;
                    jn2 = base + 2 < hi2 ? base + 2 : hi2 - 1;
                    jn3 = base + 3 < hi2 ? base + 3 : hi2 - 1;
                    n0 = S[jn0]; n1 = S[jn1]; n2 = S[jn2]; n3 = S[jn3];
                    inn0 = base < hi2; inn1 = base + 1 < hi2;
                    inn2 = base + 2 < hi2; inn3 = base + 3 < hi2;
                }
                // process current chunk (4 cands/lane)
                float dot0 = __fmaf_rn(qz, c0.z, __fmaf_rn(qy, c0.y, __fmul_rn(qx, c0.x)));
                float dist0 = __fadd_rn(__fmaf_rn(-2.f, dot0, qxx), c0.w);
                float dot1 = __fmaf_rn(qz, c1.z, __fmaf_rn(qy, c1.y, __fmul_rn(qx, c1.x)));
                float dist1 = __fadd_rn(__fmaf_rn(-2.f, dot1, qxx), c1.w);
                float dot2 = __fmaf_rn(qz, c2.z, __fmaf_rn(qy, c2.y, __fmul_rn(qx, c2.x)));
                float dist2 = __fadd_rn(__fmaf_rn(-2.f, dot2, qxx), c2.w);
                float dot3 = __fmaf_rn(qz, c3.z, __fmaf_rn(qy, c3.y, __fmul_rn(qx, c3.x)));
                float dist3 = __fadd_rn(__fmaf_rn(-2.f, dot3, qxx), c3.w);
                bool pr0 = (dist0 <= t0) && in0;
                bool pr1 = (dist1 <= t0) && in1;
                bool pr2 = (dist2 <= t0) && in2;
                bool pr3 = (dist3 <= t0) && in3;
                unsigned long long m0 = __ballot(pr0);
                unsigned long long m1 = __ballot(pr1);
                unsigned long long m2 = __ballot(pr2);
                unsigned long long m3 = __ballot(pr3);
                if (m0 | m1 | m2 | m3) {
                    unsigned n0c = (unsigned)__popcll(m0);
                    unsigned n1c = (unsigned)__popcll(m1);
                    unsigned n2c = (unsigned)__popcll(m2);
                    unsigned pos0 = cnt + (unsigned)__popcll(m0 & lt);
                    unsigned pos1 = cnt + n0c + (unsigned)__popcll(m1 & lt);
                    unsigned pos2 = cnt + n0c + n1c + (unsigned)__popcll(m2 & lt);
                    unsigned pos3 = cnt + n0c + n1c + n2c + (unsigned)__popcll(m3 & lt);
                    if (pr0 && pos0 < CAPQ) {
                        int corig = SO[jc0];
                        int db = __float_as_int(dist0);
                        unsigned key = (unsigned)db ^ (unsigned)((db >> 31) | 0x80000000);
                        pb[pos0] = ((unsigned long long)key << 32) | (unsigned)corig;
                    }
                    if (pr1 && pos1 < CAPQ) {
                        int corig = SO[jc1];
                        int db = __float_as_int(dist1);
                        unsigned key = (unsigned)db ^ (unsigned)((db >> 31) | 0x80000000);
                        pb[pos1] = ((unsigned long long)key << 32) | (unsigned)corig;
                    }
                    if (pr2 && pos2 < CAPQ) {
                        int corig = SO[jc2];
                        int db = __float_as_int(dist2);
                        unsigned key = (unsigned)db ^ (unsigned)((db >> 31) | 0x80000000);
                        pb[pos2] = ((unsigned long long)key << 32) | (unsigned)corig;
                    }
                    if (pr3 && pos3 < CAPQ) {
                        int corig = SO[jc3];
                        int db = __float_as_int(dist3);
                        unsigned key = (unsigned)db ^ (unsigned)((db >> 31) | 0x80000000);
                        pb[pos3] = ((unsigned long long)key << 32) | (unsigned)corig;
                    }
                    cnt += n0c + n1c + n2c + (unsigned)__popcll(m3);
                }
                yb = yb2; p = p2; hi = hi2; have = have2;
                jc0 = jn0; jc1 = jn1; jc2 = jn2; jc3 = jn3;
                c0 = n0; c1 = n1; c2 = n2; c3 = n3;
                in0 = inn0; in1 = inn1; in2 = inn2; in3 = inn3;
            }
            if (cnt < KN) {
                tlo = t0;
                t0 = (thi > 0.f) ? __fsqrt_rn(tlo * thi) : t0 * 2.0f;
            } else if (cnt > CAPQ) {
                thi = t0;
                t0 = (tlo > 0.f) ? __fsqrt_rn(tlo * thi) : t0 * 0.5f;
            } else break;                        // accepted: stack = all passers
        }

        // ---- selection: counting-rank over the stack (CAPQ=64 -> 1/lane) ----
        unsigned tot = cnt > CAPQ ? CAPQ : cnt;
        unsigned long long e0 = ((unsigned)lane < tot) ? pb[lane] : ~0ull;
        unsigned rank0 = 0;
        for (unsigned jx = 0; jx < tot; ++jx) {
            unsigned long long v = pb[jx];      // uniform addr -> LDS broadcast
            rank0 += (v < e0) ? 1u : 0u;
        }
        if (((unsigned)lane < tot) && rank0 < KN)
            g_idx[(b * NN + qorig) * KN + rank0] = (int)(e0 & 0xffffffffull);
    }
}

// ---------------- kernel 4: gather+max, rel, out = Wh' * rel ----------------
__global__ __launch_bounds__(256) void k_out(const float* __restrict__ Wh,
        float* __restrict__ out) {
    __shared__ float whs[CC * FE];
    int tid = threadIdx.x;
    for (int i = tid; i < CC * FE; i += 256) {
        int c = i >> 5, e = i & 31;
        float s = 0.f;
        #pragma unroll
        for (int m = 0; m < 4; ++m) s += Wh[c * 128 + m * 32 + e];
        whs[i] = s;
    }
    __syncthreads();
    int b = blockIdx.x >> 5;
    int n = ((blockIdx.x & 31) << 8) + tid;
    const int* ip = g_idx + (size_t)(b * NN + n) * KN;
    const float4* f0 = (const float4*)(g_feat0 + (size_t)b * NN * FE);
    float gmax[FE];
    #pragma unroll
    for (int e = 0; e < FE; ++e) gmax[e] = -__builtin_inff();
    for (int k = 0; k < KN; ++k) {
        int id = ip[k] & (NN - 1);      // defensive mask, no-op for valid idx
        const float4* row = f0 + (size_t)id * 8;
        #pragma unroll
        for (int e0 = 0; e0 < 8; ++e0) {
            float4 v = row[e0];
            gmax[e0 * 4 + 0] = fmaxf(gmax[e0 * 4 + 0], v.x);
            gmax[e0 * 4 + 1] = fmaxf(gmax[e0 * 4 + 1], v.y);
            gmax[e0 * 4 + 2] = fmaxf(gmax[e0 * 4 + 2], v.z);
            gmax[e0 * 4 + 3] = fmaxf(gmax[e0 * 4 + 3], v.w);
        }
    }
    const float4* selfr = f0 + (size_t)n * 8;
    float rel[FE];
    #pragma unroll
    for (int e0 = 0; e0 < 8; ++e0) {
        float4 v = selfr[e0];
        rel[e0 * 4 + 0] = gmax[e0 * 4 + 0] - v.x;
        rel[e0 * 4 + 1] = gmax[e0 * 4 + 1] - v.y;
        rel[e0 * 4 + 2] = gmax[e0 * 4 + 2] - v.z;
        rel[e0 * 4 + 3] = gmax[e0 * 4 + 3] - v.w;
    }
    float* op = out + (size_t)b * CC * NN + n;
    for (int c = 0; c < CC; ++c) {
        const float4* w4 = (const float4*)(whs + c * FE);
        float s = 0.f;
        #pragma unroll
        for (int e0 = 0; e0 < 8; ++e0) {
            float4 w = w4[e0];
            s = fmaf(w.x, rel[e0 * 4 + 0], s);
            s = fmaf(w.y, rel[e0 * 4 + 1], s);
            s = fmaf(w.z, rel[e0 * 4 + 2], s);
            s = fmaf(w.w, rel[e0 * 4 + 3], s);
        }
        op[(size_t)c * NN] = s;
    }
}

extern "C" void kernel_launch(void* const* d_in, const int* in_sizes, int n_in,
                              void* d_out, int out_size, void* d_ws, size_t ws_size,
                              hipStream_t stream) {
    const float* xyz   = (const float*)d_in[0];
    const float* feat  = (const float*)d_in[1];
    const float* gamma = (const float*)d_in[2];
    const float* beta  = (const float*)d_in[3];
    const float* Wg    = (const float*)d_in[4];
    const float* Wh    = (const float*)d_in[5];
    float* out = (float*)d_out;
    (void)d_ws; (void)ws_size;

    hipLaunchKernelGGL(k_bnstats, dim3(512),  dim3(256),  0, stream, feat);
    hipLaunchKernelGGL(k_zbin,    dim3(8),    dim3(1024), 0, stream, xyz);
    hipLaunchKernelGGL(k_feat0,   dim3(256),  dim3(256),  0, stream, feat, xyz, Wg, gamma, beta);
    hipLaunchKernelGGL(k_knn,     dim3(4096), dim3(256),  0, stream);
    hipLaunchKernelGGL(k_out,     dim3(256),  dim3(256),  0, stream, Wh, out);
}

// Round 25
// 201.381 us; speedup vs baseline: 1.1574x; 1.1574x over previous
//
#include <hip/hip_runtime.h>
#include <math.h>

#define BB 8
#define NN 8192
#define CC 64
#define FE 32
#define KN 16
#define CP3 67
#define QPW 4                 // queries per wave (one per cell-rank stratum)
#define WPB 4                 // waves per block
#define CAPQ 64               // per-query stack (count-checked => exact)
#define YB 32
#define ZB 32
#define NCELL (YB * ZB)

// Device-global scratch (module .bss). All bytes written every launch before read.
__device__ double g_part[BB * CC * 2];        // per-(b,c) BN partial sums
__device__ float g_feat0[BB * NN * FE];       // 8 MB
__device__ int   g_idx[BB * NN * KN];         // 4 MB
__device__ float4 g_sorted[BB * NN];          // cell-sorted {x,y,z,xx}
__device__ int    g_sorig[BB * NN];           // sorted -> original index
__device__ unsigned g_binoff[BB * (NCELL + 1)];

// Identical in k_zbin and k_knn (same source => same bits; monotone).
__device__ __forceinline__ int cbin(float v) {
    int bi = (int)((v + 4.5f) * (32.0f / 9.0f));   // 32 bins over [-4.5,4.5]
    if (bi < 0) bi = 0;
    if (bi > 31) bi = 31;
    return bi;
}
// FROZEN reference xx (verified R5, XLA-CPU FMA contraction)
__device__ __forceinline__ float frz_xx(float x, float y, float z) {
    return __fmaf_rn(z, z, __fmaf_rn(y, y, __fmul_rn(x, x)));
}

// ---------------- kernel 1: BN partial sums, one block per (b,c) ----------
__global__ __launch_bounds__(256) void k_bnstats(const float* __restrict__ feat) {
    int bc = blockIdx.x;                        // b*64 + c, 512 blocks
    const float* p = feat + (size_t)bc * NN;    // coalesced single stream
    int tid = threadIdx.x;
    double s = 0.0, s2 = 0.0;
    for (int n = tid; n < NN; n += 256) {
        double v = (double)p[n];
        s += v; s2 += v * v;
    }
    __shared__ double sh[256], sh2[256];
    sh[tid] = s; sh2[tid] = s2;
    __syncthreads();
    for (int off = 128; off > 0; off >>= 1) {
        if (tid < off) { sh[tid] += sh[tid + off]; sh2[tid] += sh2[tid + off]; }
        __syncthreads();
    }
    if (tid == 0) {
        g_part[bc * 2]     = sh[0];
        g_part[bc * 2 + 1] = sh2[0];
    }
}

// ---------------- kernel 1b: (y,z) cell binning -----------------------
__global__ __launch_bounds__(1024) void k_zbin(const float* __restrict__ xyz) {
    __shared__ unsigned hist[NCELL];
    __shared__ unsigned scan[NCELL];
    __shared__ unsigned boff[NCELL + 1];
    int b = blockIdx.x;
    int tid = threadIdx.x;
    hist[tid] = 0;
    __syncthreads();
    const float* bx = xyz + (size_t)b * NN * 3;
    for (int n = tid; n < NN; n += 1024) {
        float y = bx[n * 3 + 1], z = bx[n * 3 + 2];
        atomicAdd(&hist[cbin(y) * ZB + cbin(z)], 1u);
    }
    __syncthreads();
    scan[tid] = hist[tid];
    __syncthreads();
    for (int off = 1; off < NCELL; off <<= 1) {
        unsigned add = (tid >= off) ? scan[tid - off] : 0u;
        __syncthreads();
        scan[tid] += add;
        __syncthreads();
    }
    if (tid == 0) boff[0] = 0;
    boff[tid + 1] = scan[tid];
    __syncthreads();
    hist[tid] = 0;                               // reuse as cursors
    g_binoff[b * (NCELL + 1) + tid + 1] = boff[tid + 1];
    if (tid == 0) g_binoff[b * (NCELL + 1)] = 0;
    __syncthreads();
    for (int n = tid; n < NN; n += 1024) {
        const float* p = bx + (size_t)n * 3;
        float x = p[0], y = p[1], z = p[2];
        int cell = cbin(y) * ZB + cbin(z);
        unsigned pos = boff[cell] + atomicAdd(&hist[cell], 1u);
        g_sorted[(size_t)b * NN + pos] = make_float4(x, y, z, frz_xx(x, y, z));
        g_sorig[(size_t)b * NN + pos] = n;
    }
}

// ---------------- kernel 2: feat0 = Wg' * [feat;xyz] + bias0 ----------------
__global__ __launch_bounds__(256) void k_feat0(const float* __restrict__ feat,
        const float* __restrict__ xyz, const float* __restrict__ Wg,
        const float* __restrict__ gamma, const float* __restrict__ beta) {
    __shared__ float scs[CC], shs[CC];
    __shared__ float wgs[CP3 * FE];
    __shared__ float bias0[FE];
    int tid = threadIdx.x;
    if (tid < CC) {
        double s = 0.0, s2 = 0.0;
        for (int bb2 = 0; bb2 < BB; ++bb2) {
            s  += g_part[((bb2 << 6) + tid) * 2];
            s2 += g_part[((bb2 << 6) + tid) * 2 + 1];
        }
        double inv = 1.0 / (double)(BB * NN);
        double mean = s * inv;
        double var = s2 * inv - mean * mean;
        float sc = gamma[tid] * (float)(1.0 / sqrt(var + (double)1e-5f));
        scs[tid] = sc;
        shs[tid] = beta[tid] - sc * (float)mean;
    }
    __syncthreads();
    for (int i = tid; i < CP3 * FE; i += 256) {
        int c = i >> 5, e = i & 31;
        float w = Wg[e * CP3 + c];
        if (c < CC) w *= scs[c];
        wgs[c * FE + e] = w;
    }
    if (tid < FE) {
        float sacc = 0.f;
        for (int c = 0; c < CC; ++c) sacc = fmaf(Wg[tid * CP3 + c], shs[c], sacc);
        bias0[tid] = sacc;
    }
    __syncthreads();
    int b = blockIdx.x >> 5;
    int n = ((blockIdx.x & 31) << 8) + tid;
    const float* pz = xyz + ((size_t)(b * NN + n)) * 3;
    float x = pz[0], y = pz[1], z = pz[2];

    float acc[FE];
    #pragma unroll
    for (int e = 0; e < FE; ++e) acc[e] = bias0[e];
    const float* fp = feat + (size_t)b * CC * NN + n;
    for (int c = 0; c < CC; ++c) {
        float v = fp[(size_t)c * NN];
        const float4* w4 = (const float4*)(wgs + c * FE);
        #pragma unroll
        for (int e0 = 0; e0 < 8; ++e0) {
            float4 w = w4[e0];
            acc[e0 * 4 + 0] = fmaf(w.x, v, acc[e0 * 4 + 0]);
            acc[e0 * 4 + 1] = fmaf(w.y, v, acc[e0 * 4 + 1]);
            acc[e0 * 4 + 2] = fmaf(w.z, v, acc[e0 * 4 + 2]);
            acc[e0 * 4 + 3] = fmaf(w.w, v, acc[e0 * 4 + 3]);
        }
    }
    #pragma unroll
    for (int d = 0; d < 3; ++d) {
        float v = (d == 0) ? x : ((d == 1) ? y : z);
        const float4* w4 = (const float4*)(wgs + (CC + d) * FE);
        #pragma unroll
        for (int e0 = 0; e0 < 8; ++e0) {
            float4 w = w4[e0];
            acc[e0 * 4 + 0] = fmaf(w.x, v, acc[e0 * 4 + 0]);
            acc[e0 * 4 + 1] = fmaf(w.y, v, acc[e0 * 4 + 1]);
            acc[e0 * 4 + 2] = fmaf(w.z, v, acc[e0 * 4 + 2]);
            acc[e0 * 4 + 3] = fmaf(w.w, v, acc[e0 * 4 + 3]);
        }
    }
    float4* outp = (float4*)(g_feat0 + ((size_t)(b * NN + n)) * FE);
    #pragma unroll
    for (int e0 = 0; e0 < 8; ++e0)
        outp[e0] = make_float4(acc[e0 * 4 + 0], acc[e0 * 4 + 1], acc[e0 * 4 + 2], acc[e0 * 4 + 3]);
}

// ---------------- kernel 3: circle-trimmed 128-chunk stratified KNN -------
// FROZEN reference arithmetic (verified R5):
//   dot  = fma(zq,zm, fma(yq,ym, xq*xm))
//   dist = fadd( fma(-2, dot, xx_q), xx_m )
// R25 = exact revert to R23 (best measured: 200.7 us total, k_knn 128 us,
// VALUBusy 59%, occ 42%, VGPR 32). R22 (dual-stream) and R24 (4 cands/lane)
// both regressed: the {MLP depth x VGPR x chunk-waste} trade-off is locally
// optimal at 128-chunk / 2 cands/lane. Machinery: circle z-trim (R23),
// 2-D cell windows (R18), prefetch pipeline (R19/R21), gate+count-check
// [16,64], bracketed geometric bisection (R12), counting-rank (R13),
// SO[] only for passers (R15).
__global__ __launch_bounds__(256) void k_knn() {
    __shared__ unsigned long long qbuf[WPB * CAPQ];   // 2 KB
    int tid = threadIdx.x;
    int lane = tid & 63;
    int w = tid >> 6;
    int wid = blockIdx.x * WPB + w;             // 0..16383
    int b = wid >> 11;                          // 2048 waves per batch
    int g = wid & 2047;
    const float4* S = g_sorted + (size_t)b * NN;
    const int* SO = g_sorig + (size_t)b * NN;
    const unsigned* BO = g_binoff + b * (NCELL + 1);
    unsigned long long lt = (1ull << lane) - 1ull;
    unsigned long long* pb = qbuf + w * CAPQ;

    #pragma unroll 1
    for (int i = 0; i < QPW; ++i) {
        int qrank = g + (i << 11);              // stratum i sample
        float4 qv = S[qrank];
        float qx = qv.x, qy = qv.y, qz = qv.z, qxx = qv.w;
        int qorig = SO[qrank];
        float tt = 0.053f * __expf(qxx * (1.0f / 3.0f));   // ~32 expected passers
        float t0 = tt > 3.f ? 3.f : tt;
        float tlo = 0.f, thi = 0.f;             // bracket ends (0 = unset)
        unsigned cnt = 0;

        for (int attempt = 0; attempt < 40; ++attempt) {
            cnt = 0;
            float tpe = t0 + 1e-3f;
            float R = __fsqrt_rn(tpe) + 1e-3f;
            int ylo = cbin(qy - R), yhi = cbin(qy + R);

            // enter first nonempty row segment (circle-trimmed z range)
            int yb = ylo, p = 0, hi = 0;
            {
                float rowlo = 0.28125f * (float)yb - 4.5f;
                float dy = fmaxf(0.f, fmaxf(rowlo - qy, qy - (rowlo + 0.28125f)));
                float rz2 = tpe - dy * dy;
                if (rz2 > 0.f) {
                    float Rz = __fsqrt_rn(rz2) + 1e-3f;
                    int zl = cbin(qz - Rz), zh = cbin(qz + Rz);
                    p = (int)BO[yb * ZB + zl]; hi = (int)BO[yb * ZB + zh + 1];
                }
            }
            while (p >= hi && yb < yhi) {
                ++yb;
                float rowlo = 0.28125f * (float)yb - 4.5f;
                float dy = fmaxf(0.f, fmaxf(rowlo - qy, qy - (rowlo + 0.28125f)));
                float rz2 = tpe - dy * dy;
                if (rz2 > 0.f) {
                    float Rz = __fsqrt_rn(rz2) + 1e-3f;
                    int zl = cbin(qz - Rz), zh = cbin(qz + Rz);
                    p = (int)BO[yb * ZB + zl]; hi = (int)BO[yb * ZB + zh + 1];
                } else { p = 0; hi = 0; }
            }
            bool have = p < hi;
            int jc0 = 0, jc1 = 0; bool in0 = false, in1 = false;
            float4 c0, c1;
            if (have) {
                int base = p + 2 * lane;
                jc0 = base < hi ? base : hi - 1;
                jc1 = base + 1 < hi ? base + 1 : hi - 1;
                c0 = S[jc0]; c1 = S[jc1];
                in0 = base < hi; in1 = base + 1 < hi;
            }
            while (have) {
                // advance cursor (uniform) + prefetch next 128-chunk
                int yb2 = yb, p2 = p + 128, hi2 = hi;
                while (p2 >= hi2 && yb2 < yhi) {
                    ++yb2;
                    float rowlo = 0.28125f * (float)yb2 - 4.5f;
                    float dy = fmaxf(0.f, fmaxf(rowlo - qy, qy - (rowlo + 0.28125f)));
                    float rz2 = tpe - dy * dy;
                    if (rz2 > 0.f) {
                        float Rz = __fsqrt_rn(rz2) + 1e-3f;
                        int zl = cbin(qz - Rz), zh = cbin(qz + Rz);
                        p2 = (int)BO[yb2 * ZB + zl]; hi2 = (int)BO[yb2 * ZB + zh + 1];
                    } else { p2 = 0; hi2 = 0; }
                }
                bool have2 = p2 < hi2;
                int jn0 = jc0, jn1 = jc1; bool inn0 = false, inn1 = false;
                float4 n0 = c0, n1 = c1;
                if (have2) {
                    int base = p2 + 2 * lane;
                    jn0 = base < hi2 ? base : hi2 - 1;
                    jn1 = base + 1 < hi2 ? base + 1 : hi2 - 1;
                    n0 = S[jn0]; n1 = S[jn1];
                    inn0 = base < hi2; inn1 = base + 1 < hi2;
                }
                // process current chunk (2 cands/lane)
                float dot0 = __fmaf_rn(qz, c0.z, __fmaf_rn(qy, c0.y, __fmul_rn(qx, c0.x)));
                float dist0 = __fadd_rn(__fmaf_rn(-2.f, dot0, qxx), c0.w);
                float dot1 = __fmaf_rn(qz, c1.z, __fmaf_rn(qy, c1.y, __fmul_rn(qx, c1.x)));
                float dist1 = __fadd_rn(__fmaf_rn(-2.f, dot1, qxx), c1.w);
                bool pr0 = (dist0 <= t0) && in0;
                bool pr1 = (dist1 <= t0) && in1;
                unsigned long long m0 = __ballot(pr0);
                unsigned long long m1 = __ballot(pr1);
                if (m0 | m1) {
                    unsigned n0c = (unsigned)__popcll(m0);
                    unsigned pos0 = cnt + (unsigned)__popcll(m0 & lt);
                    unsigned pos1 = cnt + n0c + (unsigned)__popcll(m1 & lt);
                    if (pr0 && pos0 < CAPQ) {
                        int corig = SO[jc0];
                        int db = __float_as_int(dist0);
                        unsigned key = (unsigned)db ^ (unsigned)((db >> 31) | 0x80000000);
                        pb[pos0] = ((unsigned long long)key << 32) | (unsigned)corig;
                    }
                    if (pr1 && pos1 < CAPQ) {
                        int corig = SO[jc1];
                        int db = __float_as_int(dist1);
                        unsigned key = (unsigned)db ^ (unsigned)((db >> 31) | 0x80000000);
                        pb[pos1] = ((unsigned long long)key << 32) | (unsigned)corig;
                    }
                    cnt += n0c + (unsigned)__popcll(m1);
                }
                yb = yb2; p = p2; hi = hi2; have = have2;
                jc0 = jn0; jc1 = jn1; c0 = n0; c1 = n1; in0 = inn0; in1 = inn1;
            }
            if (cnt < KN) {
                tlo = t0;
                t0 = (thi > 0.f) ? __fsqrt_rn(tlo * thi) : t0 * 2.0f;
            } else if (cnt > CAPQ) {
                thi = t0;
                t0 = (tlo > 0.f) ? __fsqrt_rn(tlo * thi) : t0 * 0.5f;
            } else break;                        // accepted: stack = all passers
        }

        // ---- selection: counting-rank over the stack (CAPQ=64 -> 1/lane) ----
        unsigned tot = cnt > CAPQ ? CAPQ : cnt;
        unsigned long long e0 = ((unsigned)lane < tot) ? pb[lane] : ~0ull;
        unsigned rank0 = 0;
        for (unsigned jx = 0; jx < tot; ++jx) {
            unsigned long long v = pb[jx];      // uniform addr -> LDS broadcast
            rank0 += (v < e0) ? 1u : 0u;
        }
        if (((unsigned)lane < tot) && rank0 < KN)
            g_idx[(b * NN + qorig) * KN + rank0] = (int)(e0 & 0xffffffffull);
    }
}

// ---------------- kernel 4: gather+max, rel, out = Wh' * rel ----------------
__global__ __launch_bounds__(256) void k_out(const float* __restrict__ Wh,
        float* __restrict__ out) {
    __shared__ float whs[CC * FE];
    int tid = threadIdx.x;
    for (int i = tid; i < CC * FE; i += 256) {
        int c = i >> 5, e = i & 31;
        float s = 0.f;
        #pragma unroll
        for (int m = 0; m < 4; ++m) s += Wh[c * 128 + m * 32 + e];
        whs[i] = s;
    }
    __syncthreads();
    int b = blockIdx.x >> 5;
    int n = ((blockIdx.x & 31) << 8) + tid;
    const int* ip = g_idx + (size_t)(b * NN + n) * KN;
    const float4* f0 = (const float4*)(g_feat0 + (size_t)b * NN * FE);
    float gmax[FE];
    #pragma unroll
    for (int e = 0; e < FE; ++e) gmax[e] = -__builtin_inff();
    for (int k = 0; k < KN; ++k) {
        int id = ip[k] & (NN - 1);      // defensive mask, no-op for valid idx
        const float4* row = f0 + (size_t)id * 8;
        #pragma unroll
        for (int e0 = 0; e0 < 8; ++e0) {
            float4 v = row[e0];
            gmax[e0 * 4 + 0] = fmaxf(gmax[e0 * 4 + 0], v.x);
            gmax[e0 * 4 + 1] = fmaxf(gmax[e0 * 4 + 1], v.y);
            gmax[e0 * 4 + 2] = fmaxf(gmax[e0 * 4 + 2], v.z);
            gmax[e0 * 4 + 3] = fmaxf(gmax[e0 * 4 + 3], v.w);
        }
    }
    const float4* selfr = f0 + (size_t)n * 8;
    float rel[FE];
    #pragma unroll
    for (int e0 = 0; e0 < 8; ++e0) {
        float4 v = selfr[e0];
        rel[e0 * 4 + 0] = gmax[e0 * 4 + 0] - v.x;
        rel[e0 * 4 + 1] = gmax[e0 * 4 + 1] - v.y;
        rel[e0 * 4 + 2] = gmax[e0 * 4 + 2] - v.z;
        rel[e0 * 4 + 3] = gmax[e0 * 4 + 3] - v.w;
    }
    float* op = out + (size_t)b * CC * NN + n;
    for (int c = 0; c < CC; ++c) {
        const float4* w4 = (const float4*)(whs + c * FE);
        float s = 0.f;
        #pragma unroll
        for (int e0 = 0; e0 < 8; ++e0) {
            float4 w = w4[e0];
            s = fmaf(w.x, rel[e0 * 4 + 0], s);
            s = fmaf(w.y, rel[e0 * 4 + 1], s);
            s = fmaf(w.z, rel[e0 * 4 + 2], s);
            s = fmaf(w.w, rel[e0 * 4 + 3], s);
        }
        op[(size_t)c * NN] = s;
    }
}

extern "C" void kernel_launch(void* const* d_in, const int* in_sizes, int n_in,
                              void* d_out, int out_size, void* d_ws, size_t ws_size,
                              hipStream_t stream) {
    const float* xyz   = (const float*)d_in[0];
    const float* feat  = (const float*)d_in[1];
    const float* gamma = (const float*)d_in[2];
    const float* beta  = (const float*)d_in[3];
    const float* Wg    = (const float*)d_in[4];
    const float* Wh    = (const float*)d_in[5];
    float* out = (float*)d_out;
    (void)d_ws; (void)ws_size;

    hipLaunchKernelGGL(k_bnstats, dim3(512),  dim3(256),  0, stream, feat);
    hipLaunchKernelGGL(k_zbin,    dim3(8),    dim3(1024), 0, stream, xyz);
    hipLaunchKernelGGL(k_feat0,   dim3(256),  dim3(256),  0, stream, feat, xyz, Wg, gamma, beta);
    hipLaunchKernelGGL(k_knn,     dim3(4096), dim3(256),  0, stream);
    hipLaunchKernelGGL(k_out,     dim3(256),  dim3(256),  0, stream, Wh, out);
}

// Round 26
// 190.439 us; speedup vs baseline: 1.2239x; 1.0575x over previous
//
#include <hip/hip_runtime.h>
#include <math.h>

#define BB 8
#define NN 8192
#define CC 64
#define FE 32
#define KN 16
#define CP3 67
#define QPW 4                 // queries per wave (one per cell-rank stratum)
#define WPB 4                 // waves per block
#define CAPQ 64               // per-query stack (count-checked => exact)
#define YB 32
#define ZB 32
#define NCELL (YB * ZB)

// Device-global scratch (module .bss). All bytes written every launch before read.
__device__ double g_part[BB * CC * 2];        // per-(b,c) BN partial sums
__device__ float g_feat0[BB * NN * FE];       // 8 MB
__device__ int   g_idx[BB * NN * KN];         // 4 MB
__device__ float4 g_sorted[BB * NN];          // cell-sorted {x,y,z,xx}
__device__ int    g_sorig[BB * NN];           // sorted -> original index
__device__ unsigned g_binoff[BB * (NCELL + 1)];

// Identical in k_zbin and k_knn (same source => same bits; monotone).
__device__ __forceinline__ int cbin(float v) {
    int bi = (int)((v + 4.5f) * (32.0f / 9.0f));   // 32 bins over [-4.5,4.5]
    if (bi < 0) bi = 0;
    if (bi > 31) bi = 31;
    return bi;
}
// FROZEN reference xx (verified R5, XLA-CPU FMA contraction)
__device__ __forceinline__ float frz_xx(float x, float y, float z) {
    return __fmaf_rn(z, z, __fmaf_rn(y, y, __fmul_rn(x, x)));
}

// ---------------- kernel 1: BN partial sums, one block per (b,c) ----------
__global__ __launch_bounds__(256) void k_bnstats(const float* __restrict__ feat) {
    int bc = blockIdx.x;                        // b*64 + c, 512 blocks
    const float* p = feat + (size_t)bc * NN;    // coalesced single stream
    int tid = threadIdx.x;
    double s = 0.0, s2 = 0.0;
    for (int n = tid; n < NN; n += 256) {
        double v = (double)p[n];
        s += v; s2 += v * v;
    }
    __shared__ double sh[256], sh2[256];
    sh[tid] = s; sh2[tid] = s2;
    __syncthreads();
    for (int off = 128; off > 0; off >>= 1) {
        if (tid < off) { sh[tid] += sh[tid + off]; sh2[tid] += sh2[tid + off]; }
        __syncthreads();
    }
    if (tid == 0) {
        g_part[bc * 2]     = sh[0];
        g_part[bc * 2 + 1] = sh2[0];
    }
}

// ---------------- kernel 1b: (y,z) cell binning -----------------------
__global__ __launch_bounds__(1024) void k_zbin(const float* __restrict__ xyz) {
    __shared__ unsigned hist[NCELL];
    __shared__ unsigned scan[NCELL];
    __shared__ unsigned boff[NCELL + 1];
    int b = blockIdx.x;
    int tid = threadIdx.x;
    hist[tid] = 0;
    __syncthreads();
    const float* bx = xyz + (size_t)b * NN * 3;
    for (int n = tid; n < NN; n += 1024) {
        float y = bx[n * 3 + 1], z = bx[n * 3 + 2];
        atomicAdd(&hist[cbin(y) * ZB + cbin(z)], 1u);
    }
    __syncthreads();
    scan[tid] = hist[tid];
    __syncthreads();
    for (int off = 1; off < NCELL; off <<= 1) {
        unsigned add = (tid >= off) ? scan[tid - off] : 0u;
        __syncthreads();
        scan[tid] += add;
        __syncthreads();
    }
    if (tid == 0) boff[0] = 0;
    boff[tid + 1] = scan[tid];
    __syncthreads();
    hist[tid] = 0;                               // reuse as cursors
    g_binoff[b * (NCELL + 1) + tid + 1] = boff[tid + 1];
    if (tid == 0) g_binoff[b * (NCELL + 1)] = 0;
    __syncthreads();
    for (int n = tid; n < NN; n += 1024) {
        const float* p = bx + (size_t)n * 3;
        float x = p[0], y = p[1], z = p[2];
        int cell = cbin(y) * ZB + cbin(z);
        unsigned pos = boff[cell] + atomicAdd(&hist[cell], 1u);
        g_sorted[(size_t)b * NN + pos] = make_float4(x, y, z, frz_xx(x, y, z));
        g_sorig[(size_t)b * NN + pos] = n;
    }
}

// ---------------- kernel 2: feat0 = Wg' * [feat;xyz] + bias0 ----------------
// R26: 2 threads per point, each computing 16 of the 32 INDEPENDENT acc[e]
// FMA chains (chains untouched => bit-identical feat0). 512 blocks -> 8
// waves/CU (was 1 wave/SIMD). Loads duplicated per pair but line-merged.
__global__ __launch_bounds__(256) void k_feat0(const float* __restrict__ feat,
        const float* __restrict__ xyz, const float* __restrict__ Wg,
        const float* __restrict__ gamma, const float* __restrict__ beta) {
    __shared__ float scs[CC], shs[CC];
    __shared__ float wgs[CP3 * FE];
    __shared__ float bias0[FE];
    int tid = threadIdx.x;
    if (tid < CC) {
        double s = 0.0, s2 = 0.0;
        for (int bb2 = 0; bb2 < BB; ++bb2) {
            s  += g_part[((bb2 << 6) + tid) * 2];
            s2 += g_part[((bb2 << 6) + tid) * 2 + 1];
        }
        double inv = 1.0 / (double)(BB * NN);
        double mean = s * inv;
        double var = s2 * inv - mean * mean;
        float sc = gamma[tid] * (float)(1.0 / sqrt(var + (double)1e-5f));
        scs[tid] = sc;
        shs[tid] = beta[tid] - sc * (float)mean;
    }
    __syncthreads();
    for (int i = tid; i < CP3 * FE; i += 256) {
        int c = i >> 5, e = i & 31;
        float w = Wg[e * CP3 + c];
        if (c < CC) w *= scs[c];
        wgs[c * FE + e] = w;
    }
    if (tid < FE) {
        float sacc = 0.f;
        for (int c = 0; c < CC; ++c) sacc = fmaf(Wg[tid * CP3 + c], shs[c], sacc);
        bias0[tid] = sacc;
    }
    __syncthreads();
    int pid = blockIdx.x * 128 + (tid >> 1);    // 512 blocks x 128 points
    int half = tid & 1;
    int b = pid >> 13;
    int n = pid & (NN - 1);
    const float* pz = xyz + ((size_t)(b * NN + n)) * 3;
    float x = pz[0], y = pz[1], z = pz[2];

    float acc[16];
    #pragma unroll
    for (int e = 0; e < 16; ++e) acc[e] = bias0[half * 16 + e];
    const float* fp = feat + (size_t)b * CC * NN + n;
    for (int c = 0; c < CC; ++c) {
        float v = fp[(size_t)c * NN];
        const float4* w4 = (const float4*)(wgs + c * FE) + half * 4;
        #pragma unroll
        for (int e0 = 0; e0 < 4; ++e0) {
            float4 w = w4[e0];
            acc[e0 * 4 + 0] = fmaf(w.x, v, acc[e0 * 4 + 0]);
            acc[e0 * 4 + 1] = fmaf(w.y, v, acc[e0 * 4 + 1]);
            acc[e0 * 4 + 2] = fmaf(w.z, v, acc[e0 * 4 + 2]);
            acc[e0 * 4 + 3] = fmaf(w.w, v, acc[e0 * 4 + 3]);
        }
    }
    #pragma unroll
    for (int d = 0; d < 3; ++d) {
        float v = (d == 0) ? x : ((d == 1) ? y : z);
        const float4* w4 = (const float4*)(wgs + (CC + d) * FE) + half * 4;
        #pragma unroll
        for (int e0 = 0; e0 < 4; ++e0) {
            float4 w = w4[e0];
            acc[e0 * 4 + 0] = fmaf(w.x, v, acc[e0 * 4 + 0]);
            acc[e0 * 4 + 1] = fmaf(w.y, v, acc[e0 * 4 + 1]);
            acc[e0 * 4 + 2] = fmaf(w.z, v, acc[e0 * 4 + 2]);
            acc[e0 * 4 + 3] = fmaf(w.w, v, acc[e0 * 4 + 3]);
        }
    }
    float4* outp = ((float4*)(g_feat0 + ((size_t)(b * NN + n)) * FE)) + half * 4;
    #pragma unroll
    for (int e0 = 0; e0 < 4; ++e0)
        outp[e0] = make_float4(acc[e0 * 4 + 0], acc[e0 * 4 + 1], acc[e0 * 4 + 2], acc[e0 * 4 + 3]);
}

// ---------------- kernel 3: circle-trimmed 128-chunk stratified KNN -------
// FROZEN reference arithmetic (verified R5); R23/R25 proven configuration.
__global__ __launch_bounds__(256) void k_knn() {
    __shared__ unsigned long long qbuf[WPB * CAPQ];   // 2 KB
    int tid = threadIdx.x;
    int lane = tid & 63;
    int w = tid >> 6;
    int wid = blockIdx.x * WPB + w;             // 0..16383
    int b = wid >> 11;                          // 2048 waves per batch
    int g = wid & 2047;
    const float4* S = g_sorted + (size_t)b * NN;
    const int* SO = g_sorig + (size_t)b * NN;
    const unsigned* BO = g_binoff + b * (NCELL + 1);
    unsigned long long lt = (1ull << lane) - 1ull;
    unsigned long long* pb = qbuf + w * CAPQ;

    #pragma unroll 1
    for (int i = 0; i < QPW; ++i) {
        int qrank = g + (i << 11);              // stratum i sample
        float4 qv = S[qrank];
        float qx = qv.x, qy = qv.y, qz = qv.z, qxx = qv.w;
        int qorig = SO[qrank];
        float tt = 0.053f * __expf(qxx * (1.0f / 3.0f));   // ~32 expected passers
        float t0 = tt > 3.f ? 3.f : tt;
        float tlo = 0.f, thi = 0.f;             // bracket ends (0 = unset)
        unsigned cnt = 0;

        for (int attempt = 0; attempt < 40; ++attempt) {
            cnt = 0;
            float tpe = t0 + 1e-3f;
            float R = __fsqrt_rn(tpe) + 1e-3f;
            int ylo = cbin(qy - R), yhi = cbin(qy + R);

            // enter first nonempty row segment (circle-trimmed z range)
            int yb = ylo, p = 0, hi = 0;
            {
                float rowlo = 0.28125f * (float)yb - 4.5f;
                float dy = fmaxf(0.f, fmaxf(rowlo - qy, qy - (rowlo + 0.28125f)));
                float rz2 = tpe - dy * dy;
                if (rz2 > 0.f) {
                    float Rz = __fsqrt_rn(rz2) + 1e-3f;
                    int zl = cbin(qz - Rz), zh = cbin(qz + Rz);
                    p = (int)BO[yb * ZB + zl]; hi = (int)BO[yb * ZB + zh + 1];
                }
            }
            while (p >= hi && yb < yhi) {
                ++yb;
                float rowlo = 0.28125f * (float)yb - 4.5f;
                float dy = fmaxf(0.f, fmaxf(rowlo - qy, qy - (rowlo + 0.28125f)));
                float rz2 = tpe - dy * dy;
                if (rz2 > 0.f) {
                    float Rz = __fsqrt_rn(rz2) + 1e-3f;
                    int zl = cbin(qz - Rz), zh = cbin(qz + Rz);
                    p = (int)BO[yb * ZB + zl]; hi = (int)BO[yb * ZB + zh + 1];
                } else { p = 0; hi = 0; }
            }
            bool have = p < hi;
            int jc0 = 0, jc1 = 0; bool in0 = false, in1 = false;
            float4 c0, c1;
            if (have) {
                int base = p + 2 * lane;
                jc0 = base < hi ? base : hi - 1;
                jc1 = base + 1 < hi ? base + 1 : hi - 1;
                c0 = S[jc0]; c1 = S[jc1];
                in0 = base < hi; in1 = base + 1 < hi;
            }
            while (have) {
                // advance cursor (uniform) + prefetch next 128-chunk
                int yb2 = yb, p2 = p + 128, hi2 = hi;
                while (p2 >= hi2 && yb2 < yhi) {
                    ++yb2;
                    float rowlo = 0.28125f * (float)yb2 - 4.5f;
                    float dy = fmaxf(0.f, fmaxf(rowlo - qy, qy - (rowlo + 0.28125f)));
                    float rz2 = tpe - dy * dy;
                    if (rz2 > 0.f) {
                        float Rz = __fsqrt_rn(rz2) + 1e-3f;
                        int zl = cbin(qz - Rz), zh = cbin(qz + Rz);
                        p2 = (int)BO[yb2 * ZB + zl]; hi2 = (int)BO[yb2 * ZB + zh + 1];
                    } else { p2 = 0; hi2 = 0; }
                }
                bool have2 = p2 < hi2;
                int jn0 = jc0, jn1 = jc1; bool inn0 = false, inn1 = false;
                float4 n0 = c0, n1 = c1;
                if (have2) {
                    int base = p2 + 2 * lane;
                    jn0 = base < hi2 ? base : hi2 - 1;
                    jn1 = base + 1 < hi2 ? base + 1 : hi2 - 1;
                    n0 = S[jn0]; n1 = S[jn1];
                    inn0 = base < hi2; inn1 = base + 1 < hi2;
                }
                // process current chunk (2 cands/lane)
                float dot0 = __fmaf_rn(qz, c0.z, __fmaf_rn(qy, c0.y, __fmul_rn(qx, c0.x)));
                float dist0 = __fadd_rn(__fmaf_rn(-2.f, dot0, qxx), c0.w);
                float dot1 = __fmaf_rn(qz, c1.z, __fmaf_rn(qy, c1.y, __fmul_rn(qx, c1.x)));
                float dist1 = __fadd_rn(__fmaf_rn(-2.f, dot1, qxx), c1.w);
                bool pr0 = (dist0 <= t0) && in0;
                bool pr1 = (dist1 <= t0) && in1;
                unsigned long long m0 = __ballot(pr0);
                unsigned long long m1 = __ballot(pr1);
                if (m0 | m1) {
                    unsigned n0c = (unsigned)__popcll(m0);
                    unsigned pos0 = cnt + (unsigned)__popcll(m0 & lt);
                    unsigned pos1 = cnt + n0c + (unsigned)__popcll(m1 & lt);
                    if (pr0 && pos0 < CAPQ) {
                        int corig = SO[jc0];
                        int db = __float_as_int(dist0);
                        unsigned key = (unsigned)db ^ (unsigned)((db >> 31) | 0x80000000);
                        pb[pos0] = ((unsigned long long)key << 32) | (unsigned)corig;
                    }
                    if (pr1 && pos1 < CAPQ) {
                        int corig = SO[jc1];
                        int db = __float_as_int(dist1);
                        unsigned key = (unsigned)db ^ (unsigned)((db >> 31) | 0x80000000);
                        pb[pos1] = ((unsigned long long)key << 32) | (unsigned)corig;
                    }
                    cnt += n0c + (unsigned)__popcll(m1);
                }
                yb = yb2; p = p2; hi = hi2; have = have2;
                jc0 = jn0; jc1 = jn1; c0 = n0; c1 = n1; in0 = inn0; in1 = inn1;
            }
            if (cnt < KN) {
                tlo = t0;
                t0 = (thi > 0.f) ? __fsqrt_rn(tlo * thi) : t0 * 2.0f;
            } else if (cnt > CAPQ) {
                thi = t0;
                t0 = (tlo > 0.f) ? __fsqrt_rn(tlo * thi) : t0 * 0.5f;
            } else break;                        // accepted: stack = all passers
        }

        // ---- selection: counting-rank over the stack (CAPQ=64 -> 1/lane) ----
        unsigned tot = cnt > CAPQ ? CAPQ : cnt;
        unsigned long long e0 = ((unsigned)lane < tot) ? pb[lane] : ~0ull;
        unsigned rank0 = 0;
        for (unsigned jx = 0; jx < tot; ++jx) {
            unsigned long long v = pb[jx];      // uniform addr -> LDS broadcast
            rank0 += (v < e0) ? 1u : 0u;
        }
        if (((unsigned)lane < tot) && rank0 < KN)
            g_idx[(b * NN + qorig) * KN + rank0] = (int)(e0 & 0xffffffffull);
    }
}

// ---------------- kernel 4: gather+max, rel, out = Wh' * rel ----------------
// R26: 4 threads per point -- each gathers 4 of 16 neighbors (fmax is
// exactly associative/commutative => identical bits), partials combined via
// padded LDS (stride 33 => <=2-way bank aliasing, free), then the 4 threads
// split the 64 output channels (per-channel dot untouched => identical
// bits). 1024 blocks -> 16 waves/CU (was 1 wave/SIMD).
__global__ __launch_bounds__(256) void k_out(const float* __restrict__ Wh,
        float* __restrict__ out) {
    __shared__ float whs[CC * FE];
    __shared__ float pmax[64][4][33];           // ~33.8 KB, padded
    int tid = threadIdx.x;
    for (int i = tid; i < CC * FE; i += 256) {
        int c = i >> 5, e = i & 31;
        float s = 0.f;
        #pragma unroll
        for (int m = 0; m < 4; ++m) s += Wh[c * 128 + m * 32 + e];
        whs[i] = s;
    }
    int pt = tid >> 2, part = tid & 3;
    int pid = blockIdx.x * 64 + pt;             // 1024 blocks x 64 points
    int b = pid >> 13;
    int n = pid & (NN - 1);
    const int* ip = g_idx + (size_t)(b * NN + n) * KN + part * 4;
    const float4* f0 = (const float4*)(g_feat0 + (size_t)b * NN * FE);
    float gm[FE];
    #pragma unroll
    for (int e = 0; e < FE; ++e) gm[e] = -__builtin_inff();
    #pragma unroll
    for (int k = 0; k < 4; ++k) {
        int id = ip[k] & (NN - 1);      // defensive mask, no-op for valid idx
        const float4* row = f0 + (size_t)id * 8;
        #pragma unroll
        for (int e0 = 0; e0 < 8; ++e0) {
            float4 v = row[e0];
            gm[e0 * 4 + 0] = fmaxf(gm[e0 * 4 + 0], v.x);
            gm[e0 * 4 + 1] = fmaxf(gm[e0 * 4 + 1], v.y);
            gm[e0 * 4 + 2] = fmaxf(gm[e0 * 4 + 2], v.z);
            gm[e0 * 4 + 3] = fmaxf(gm[e0 * 4 + 3], v.w);
        }
    }
    #pragma unroll
    for (int e = 0; e < FE; ++e) pmax[pt][part][e] = gm[e];
    __syncthreads();

    const float4* selfr = f0 + (size_t)n * 8;
    float rel[FE];
    #pragma unroll
    for (int e0 = 0; e0 < 8; ++e0) {
        float4 v = selfr[e0];
        #pragma unroll
        for (int j = 0; j < 4; ++j) {
            int e = e0 * 4 + j;
            float gg = fmaxf(fmaxf(pmax[pt][0][e], pmax[pt][1][e]),
                             fmaxf(pmax[pt][2][e], pmax[pt][3][e]));
            float sv = (j == 0) ? v.x : (j == 1) ? v.y : (j == 2) ? v.z : v.w;
            rel[e] = gg - sv;
        }
    }
    float* op = out + (size_t)b * CC * NN + n;
    for (int c = part * 16; c < part * 16 + 16; ++c) {
        const float4* w4 = (const float4*)(whs + c * FE);
        float s = 0.f;
        #pragma unroll
        for (int e0 = 0; e0 < 8; ++e0) {
            float4 w = w4[e0];
            s = fmaf(w.x, rel[e0 * 4 + 0], s);
            s = fmaf(w.y, rel[e0 * 4 + 1], s);
            s = fmaf(w.z, rel[e0 * 4 + 2], s);
            s = fmaf(w.w, rel[e0 * 4 + 3], s);
        }
        op[(size_t)c * NN] = s;
    }
}

extern "C" void kernel_launch(void* const* d_in, const int* in_sizes, int n_in,
                              void* d_out, int out_size, void* d_ws, size_t ws_size,
                              hipStream_t stream) {
    const float* xyz   = (const float*)d_in[0];
    const float* feat  = (const float*)d_in[1];
    const float* gamma = (const float*)d_in[2];
    const float* beta  = (const float*)d_in[3];
    const float* Wg    = (const float*)d_in[4];
    const float* Wh    = (const float*)d_in[5];
    float* out = (float*)d_out;
    (void)d_ws; (void)ws_size;

    hipLaunchKernelGGL(k_bnstats, dim3(512),  dim3(256),  0, stream, feat);
    hipLaunchKernelGGL(k_zbin,    dim3(8),    dim3(1024), 0, stream, xyz);
    hipLaunchKernelGGL(k_feat0,   dim3(512),  dim3(256),  0, stream, feat, xyz, Wg, gamma, beta);
    hipLaunchKernelGGL(k_knn,     dim3(4096), dim3(256),  0, stream);
    hipLaunchKernelGGL(k_out,     dim3(1024), dim3(256),  0, stream, Wh, out);
}

// Round 27
// 178.903 us; speedup vs baseline: 1.3028x; 1.0645x over previous
//
#include <hip/hip_runtime.h>
#include <math.h>

#define BB 8
#define NN 8192
#define CC 64
#define FE 32
#define KN 16
#define CP3 67
#define QPW 4                 // queries per wave (one per cell-rank stratum)
#define WPB 4                 // waves per block
#define CAPQ 64               // per-query stack (count-checked => exact)
#define YB 32
#define ZB 32
#define NCELL (YB * ZB)
#define NSL 8                 // scatter slices per batch

// Device-global scratch (module .bss). All bytes written every launch before read.
__device__ double g_part[BB * CC * 2];        // per-(b,c) BN partial sums
__device__ float g_feat0[BB * NN * FE];       // 8 MB
__device__ int   g_idx[BB * NN * KN];         // 4 MB
__device__ float4 g_sorted[BB * NN];          // cell-sorted {x,y,z,xx}
__device__ int    g_sorig[BB * NN];           // sorted -> original index
__device__ unsigned g_binoff[BB * (NCELL + 1)];
__device__ unsigned g_parthist[BB * NSL * NCELL];   // per-slice cell histograms

// Identical in binning and k_knn (same source => same bits; monotone).
__device__ __forceinline__ int cbin(float v) {
    int bi = (int)((v + 4.5f) * (32.0f / 9.0f));   // 32 bins over [-4.5,4.5]
    if (bi < 0) bi = 0;
    if (bi > 31) bi = 31;
    return bi;
}
// FROZEN reference xx (verified R5, XLA-CPU FMA contraction)
__device__ __forceinline__ float frz_xx(float x, float y, float z) {
    return __fmaf_rn(z, z, __fmaf_rn(y, y, __fmul_rn(x, x)));
}

// ---------------- kernel 1: BN partial sums, one block per (b,c) ----------
__global__ __launch_bounds__(256) void k_bnstats(const float* __restrict__ feat) {
    int bc = blockIdx.x;                        // b*64 + c, 512 blocks
    const float* p = feat + (size_t)bc * NN;    // coalesced single stream
    int tid = threadIdx.x;
    double s = 0.0, s2 = 0.0;
    for (int n = tid; n < NN; n += 256) {
        double v = (double)p[n];
        s += v; s2 += v * v;
    }
    __shared__ double sh[256], sh2[256];
    sh[tid] = s; sh2[tid] = s2;
    __syncthreads();
    for (int off = 128; off > 0; off >>= 1) {
        if (tid < off) { sh[tid] += sh[tid + off]; sh2[tid] += sh2[tid + off]; }
        __syncthreads();
    }
    if (tid == 0) {
        g_part[bc * 2]     = sh[0];
        g_part[bc * 2 + 1] = sh2[0];
    }
}

// ---------------- binning phase (R27: 3 wide kernels, was 8-block monolith) -
// Intra-cell order becomes nondeterministic (LDS cursor atomics) but output
// is invariant: counting-rank sorts by (dist,idx) key, count-check needs
// only the passer SET, g_sorig stays bijective => g_idx bits unchanged.
__global__ __launch_bounds__(1024) void k_hist(const float* __restrict__ xyz) {
    __shared__ unsigned hist[NCELL];
    int blk = blockIdx.x;                       // 64 = 8 batches x 8 slices
    int b = blk >> 3, si = blk & 7;
    int tid = threadIdx.x;
    hist[tid] = 0;
    __syncthreads();
    int n = si * 1024 + tid;
    const float* p = xyz + ((size_t)(b * NN + n)) * 3;
    atomicAdd(&hist[cbin(p[1]) * ZB + cbin(p[2])], 1u);
    __syncthreads();
    g_parthist[(size_t)(b * NSL + si) * NCELL + tid] = hist[tid];
}

__global__ __launch_bounds__(1024) void k_scan() {
    __shared__ unsigned scan[NCELL];
    int b = blockIdx.x;
    int tid = threadIdx.x;
    unsigned s = 0;
    #pragma unroll
    for (int si = 0; si < NSL; ++si)
        s += g_parthist[(size_t)(b * NSL + si) * NCELL + tid];
    scan[tid] = s;
    __syncthreads();
    for (int off = 1; off < NCELL; off <<= 1) {
        unsigned add = (tid >= off) ? scan[tid - off] : 0u;
        __syncthreads();
        scan[tid] += add;
        __syncthreads();
    }
    g_binoff[b * (NCELL + 1) + tid + 1] = scan[tid];
    if (tid == 0) g_binoff[b * (NCELL + 1)] = 0;
}

__global__ __launch_bounds__(1024) void k_scatter(const float* __restrict__ xyz) {
    __shared__ unsigned cur[NCELL];
    int blk = blockIdx.x;                       // 64
    int b = blk >> 3, si = blk & 7;
    int tid = threadIdx.x;
    unsigned base = g_binoff[b * (NCELL + 1) + tid];
    for (int s2 = 0; s2 < si; ++s2)
        base += g_parthist[(size_t)(b * NSL + s2) * NCELL + tid];
    cur[tid] = base;
    __syncthreads();
    int n = si * 1024 + tid;
    const float* p = xyz + ((size_t)(b * NN + n)) * 3;
    float x = p[0], y = p[1], z = p[2];
    int cell = cbin(y) * ZB + cbin(z);
    unsigned pos = atomicAdd(&cur[cell], 1u);
    g_sorted[(size_t)b * NN + pos] = make_float4(x, y, z, frz_xx(x, y, z));
    g_sorig[(size_t)b * NN + pos] = n;
}

// ---------------- kernel 2: feat0 = Wg' * [feat;xyz] + bias0 ----------------
// R26-proven: 2 threads/point, 16 independent acc chains each (bit-identical).
__global__ __launch_bounds__(256) void k_feat0(const float* __restrict__ feat,
        const float* __restrict__ xyz, const float* __restrict__ Wg,
        const float* __restrict__ gamma, const float* __restrict__ beta) {
    __shared__ float scs[CC], shs[CC];
    __shared__ float wgs[CP3 * FE];
    __shared__ float bias0[FE];
    int tid = threadIdx.x;
    if (tid < CC) {
        double s = 0.0, s2 = 0.0;
        for (int bb2 = 0; bb2 < BB; ++bb2) {
            s  += g_part[((bb2 << 6) + tid) * 2];
            s2 += g_part[((bb2 << 6) + tid) * 2 + 1];
        }
        double inv = 1.0 / (double)(BB * NN);
        double mean = s * inv;
        double var = s2 * inv - mean * mean;
        float sc = gamma[tid] * (float)(1.0 / sqrt(var + (double)1e-5f));
        scs[tid] = sc;
        shs[tid] = beta[tid] - sc * (float)mean;
    }
    __syncthreads();
    for (int i = tid; i < CP3 * FE; i += 256) {
        int c = i >> 5, e = i & 31;
        float w = Wg[e * CP3 + c];
        if (c < CC) w *= scs[c];
        wgs[c * FE + e] = w;
    }
    if (tid < FE) {
        float sacc = 0.f;
        for (int c = 0; c < CC; ++c) sacc = fmaf(Wg[tid * CP3 + c], shs[c], sacc);
        bias0[tid] = sacc;
    }
    __syncthreads();
    int pid = blockIdx.x * 128 + (tid >> 1);    // 512 blocks x 128 points
    int half = tid & 1;
    int b = pid >> 13;
    int n = pid & (NN - 1);
    const float* pz = xyz + ((size_t)(b * NN + n)) * 3;
    float x = pz[0], y = pz[1], z = pz[2];

    float acc[16];
    #pragma unroll
    for (int e = 0; e < 16; ++e) acc[e] = bias0[half * 16 + e];
    const float* fp = feat + (size_t)b * CC * NN + n;
    for (int c = 0; c < CC; ++c) {
        float v = fp[(size_t)c * NN];
        const float4* w4 = (const float4*)(wgs + c * FE) + half * 4;
        #pragma unroll
        for (int e0 = 0; e0 < 4; ++e0) {
            float4 w = w4[e0];
            acc[e0 * 4 + 0] = fmaf(w.x, v, acc[e0 * 4 + 0]);
            acc[e0 * 4 + 1] = fmaf(w.y, v, acc[e0 * 4 + 1]);
            acc[e0 * 4 + 2] = fmaf(w.z, v, acc[e0 * 4 + 2]);
            acc[e0 * 4 + 3] = fmaf(w.w, v, acc[e0 * 4 + 3]);
        }
    }
    #pragma unroll
    for (int d = 0; d < 3; ++d) {
        float v = (d == 0) ? x : ((d == 1) ? y : z);
        const float4* w4 = (const float4*)(wgs + (CC + d) * FE) + half * 4;
        #pragma unroll
        for (int e0 = 0; e0 < 4; ++e0) {
            float4 w = w4[e0];
            acc[e0 * 4 + 0] = fmaf(w.x, v, acc[e0 * 4 + 0]);
            acc[e0 * 4 + 1] = fmaf(w.y, v, acc[e0 * 4 + 1]);
            acc[e0 * 4 + 2] = fmaf(w.z, v, acc[e0 * 4 + 2]);
            acc[e0 * 4 + 3] = fmaf(w.w, v, acc[e0 * 4 + 3]);
        }
    }
    float4* outp = ((float4*)(g_feat0 + ((size_t)(b * NN + n)) * FE)) + half * 4;
    #pragma unroll
    for (int e0 = 0; e0 < 4; ++e0)
        outp[e0] = make_float4(acc[e0 * 4 + 0], acc[e0 * 4 + 1], acc[e0 * 4 + 2], acc[e0 * 4 + 3]);
}

// ---------------- kernel 3: circle-trimmed 128-chunk stratified KNN -------
// FROZEN reference arithmetic (verified R5); R23/R25 proven configuration.
// R27: gate coef 0.053 -> 0.045 (~27 expected passers): ~10-15% fewer evals;
// retry P(cnt<16) ~1.4%, bracketed bisection provably recovers => exactness
// unchanged (count-check + bisection independent of the initial guess).
__global__ __launch_bounds__(256) void k_knn() {
    __shared__ unsigned long long qbuf[WPB * CAPQ];   // 2 KB
    int tid = threadIdx.x;
    int lane = tid & 63;
    int w = tid >> 6;
    int wid = blockIdx.x * WPB + w;             // 0..16383
    int b = wid >> 11;                          // 2048 waves per batch
    int g = wid & 2047;
    const float4* S = g_sorted + (size_t)b * NN;
    const int* SO = g_sorig + (size_t)b * NN;
    const unsigned* BO = g_binoff + b * (NCELL + 1);
    unsigned long long lt = (1ull << lane) - 1ull;
    unsigned long long* pb = qbuf + w * CAPQ;

    #pragma unroll 1
    for (int i = 0; i < QPW; ++i) {
        int qrank = g + (i << 11);              // stratum i sample
        float4 qv = S[qrank];
        float qx = qv.x, qy = qv.y, qz = qv.z, qxx = qv.w;
        int qorig = SO[qrank];
        float tt = 0.045f * __expf(qxx * (1.0f / 3.0f));   // ~27 expected passers
        float t0 = tt > 3.f ? 3.f : tt;
        float tlo = 0.f, thi = 0.f;             // bracket ends (0 = unset)
        unsigned cnt = 0;

        for (int attempt = 0; attempt < 40; ++attempt) {
            cnt = 0;
            float tpe = t0 + 1e-3f;
            float R = __fsqrt_rn(tpe) + 1e-3f;
            int ylo = cbin(qy - R), yhi = cbin(qy + R);

            // enter first nonempty row segment (circle-trimmed z range)
            int yb = ylo, p = 0, hi = 0;
            {
                float rowlo = 0.28125f * (float)yb - 4.5f;
                float dy = fmaxf(0.f, fmaxf(rowlo - qy, qy - (rowlo + 0.28125f)));
                float rz2 = tpe - dy * dy;
                if (rz2 > 0.f) {
                    float Rz = __fsqrt_rn(rz2) + 1e-3f;
                    int zl = cbin(qz - Rz), zh = cbin(qz + Rz);
                    p = (int)BO[yb * ZB + zl]; hi = (int)BO[yb * ZB + zh + 1];
                }
            }
            while (p >= hi && yb < yhi) {
                ++yb;
                float rowlo = 0.28125f * (float)yb - 4.5f;
                float dy = fmaxf(0.f, fmaxf(rowlo - qy, qy - (rowlo + 0.28125f)));
                float rz2 = tpe - dy * dy;
                if (rz2 > 0.f) {
                    float Rz = __fsqrt_rn(rz2) + 1e-3f;
                    int zl = cbin(qz - Rz), zh = cbin(qz + Rz);
                    p = (int)BO[yb * ZB + zl]; hi = (int)BO[yb * ZB + zh + 1];
                } else { p = 0; hi = 0; }
            }
            bool have = p < hi;
            int jc0 = 0, jc1 = 0; bool in0 = false, in1 = false;
            float4 c0, c1;
            if (have) {
                int base = p + 2 * lane;
                jc0 = base < hi ? base : hi - 1;
                jc1 = base + 1 < hi ? base + 1 : hi - 1;
                c0 = S[jc0]; c1 = S[jc1];
                in0 = base < hi; in1 = base + 1 < hi;
            }
            while (have) {
                // advance cursor (uniform) + prefetch next 128-chunk
                int yb2 = yb, p2 = p + 128, hi2 = hi;
                while (p2 >= hi2 && yb2 < yhi) {
                    ++yb2;
                    float rowlo = 0.28125f * (float)yb2 - 4.5f;
                    float dy = fmaxf(0.f, fmaxf(rowlo - qy, qy - (rowlo + 0.28125f)));
                    float rz2 = tpe - dy * dy;
                    if (rz2 > 0.f) {
                        float Rz = __fsqrt_rn(rz2) + 1e-3f;
                        int zl = cbin(qz - Rz), zh = cbin(qz + Rz);
                        p2 = (int)BO[yb2 * ZB + zl]; hi2 = (int)BO[yb2 * ZB + zh + 1];
                    } else { p2 = 0; hi2 = 0; }
                }
                bool have2 = p2 < hi2;
                int jn0 = jc0, jn1 = jc1; bool inn0 = false, inn1 = false;
                float4 n0 = c0, n1 = c1;
                if (have2) {
                    int base = p2 + 2 * lane;
                    jn0 = base < hi2 ? base : hi2 - 1;
                    jn1 = base + 1 < hi2 ? base + 1 : hi2 - 1;
                    n0 = S[jn0]; n1 = S[jn1];
                    inn0 = base < hi2; inn1 = base + 1 < hi2;
                }
                // process current chunk (2 cands/lane)
                float dot0 = __fmaf_rn(qz, c0.z, __fmaf_rn(qy, c0.y, __fmul_rn(qx, c0.x)));
                float dist0 = __fadd_rn(__fmaf_rn(-2.f, dot0, qxx), c0.w);
                float dot1 = __fmaf_rn(qz, c1.z, __fmaf_rn(qy, c1.y, __fmul_rn(qx, c1.x)));
                float dist1 = __fadd_rn(__fmaf_rn(-2.f, dot1, qxx), c1.w);
                bool pr0 = (dist0 <= t0) && in0;
                bool pr1 = (dist1 <= t0) && in1;
                unsigned long long m0 = __ballot(pr0);
                unsigned long long m1 = __ballot(pr1);
                if (m0 | m1) {
                    unsigned n0c = (unsigned)__popcll(m0);
                    unsigned pos0 = cnt + (unsigned)__popcll(m0 & lt);
                    unsigned pos1 = cnt + n0c + (unsigned)__popcll(m1 & lt);
                    if (pr0 && pos0 < CAPQ) {
                        int corig = SO[jc0];
                        int db = __float_as_int(dist0);
                        unsigned key = (unsigned)db ^ (unsigned)((db >> 31) | 0x80000000);
                        pb[pos0] = ((unsigned long long)key << 32) | (unsigned)corig;
                    }
                    if (pr1 && pos1 < CAPQ) {
                        int corig = SO[jc1];
                        int db = __float_as_int(dist1);
                        unsigned key = (unsigned)db ^ (unsigned)((db >> 31) | 0x80000000);
                        pb[pos1] = ((unsigned long long)key << 32) | (unsigned)corig;
                    }
                    cnt += n0c + (unsigned)__popcll(m1);
                }
                yb = yb2; p = p2; hi = hi2; have = have2;
                jc0 = jn0; jc1 = jn1; c0 = n0; c1 = n1; in0 = inn0; in1 = inn1;
            }
            if (cnt < KN) {
                tlo = t0;
                t0 = (thi > 0.f) ? __fsqrt_rn(tlo * thi) : t0 * 2.0f;
            } else if (cnt > CAPQ) {
                thi = t0;
                t0 = (tlo > 0.f) ? __fsqrt_rn(tlo * thi) : t0 * 0.5f;
            } else break;                        // accepted: stack = all passers
        }

        // ---- selection: counting-rank over the stack (CAPQ=64 -> 1/lane) ----
        unsigned tot = cnt > CAPQ ? CAPQ : cnt;
        unsigned long long e0 = ((unsigned)lane < tot) ? pb[lane] : ~0ull;
        unsigned rank0 = 0;
        for (unsigned jx = 0; jx < tot; ++jx) {
            unsigned long long v = pb[jx];      // uniform addr -> LDS broadcast
            rank0 += (v < e0) ? 1u : 0u;
        }
        if (((unsigned)lane < tot) && rank0 < KN)
            g_idx[(b * NN + qorig) * KN + rank0] = (int)(e0 & 0xffffffffull);
    }
}

// ---------------- kernel 4: gather+max, rel, out = Wh' * rel ----------------
// R26-proven: 4 threads/point (fmax exact-assoc), padded LDS combine,
// channel split. 1024 blocks -> 16 waves/CU.
__global__ __launch_bounds__(256) void k_out(const float* __restrict__ Wh,
        float* __restrict__ out) {
    __shared__ float whs[CC * FE];
    __shared__ float pmax[64][4][33];           // ~33.8 KB, padded
    int tid = threadIdx.x;
    for (int i = tid; i < CC * FE; i += 256) {
        int c = i >> 5, e = i & 31;
        float s = 0.f;
        #pragma unroll
        for (int m = 0; m < 4; ++m) s += Wh[c * 128 + m * 32 + e];
        whs[i] = s;
    }
    int pt = tid >> 2, part = tid & 3;
    int pid = blockIdx.x * 64 + pt;             // 1024 blocks x 64 points
    int b = pid >> 13;
    int n = pid & (NN - 1);
    const int* ip = g_idx + (size_t)(b * NN + n) * KN + part * 4;
    const float4* f0 = (const float4*)(g_feat0 + (size_t)b * NN * FE);
    float gm[FE];
    #pragma unroll
    for (int e = 0; e < FE; ++e) gm[e] = -__builtin_inff();
    #pragma unroll
    for (int k = 0; k < 4; ++k) {
        int id = ip[k] & (NN - 1);      // defensive mask, no-op for valid idx
        const float4* row = f0 + (size_t)id * 8;
        #pragma unroll
        for (int e0 = 0; e0 < 8; ++e0) {
            float4 v = row[e0];
            gm[e0 * 4 + 0] = fmaxf(gm[e0 * 4 + 0], v.x);
            gm[e0 * 4 + 1] = fmaxf(gm[e0 * 4 + 1], v.y);
            gm[e0 * 4 + 2] = fmaxf(gm[e0 * 4 + 2], v.z);
            gm[e0 * 4 + 3] = fmaxf(gm[e0 * 4 + 3], v.w);
        }
    }
    #pragma unroll
    for (int e = 0; e < FE; ++e) pmax[pt][part][e] = gm[e];
    __syncthreads();

    const float4* selfr = f0 + (size_t)n * 8;
    float rel[FE];
    #pragma unroll
    for (int e0 = 0; e0 < 8; ++e0) {
        float4 v = selfr[e0];
        #pragma unroll
        for (int j = 0; j < 4; ++j) {
            int e = e0 * 4 + j;
            float gg = fmaxf(fmaxf(pmax[pt][0][e], pmax[pt][1][e]),
                             fmaxf(pmax[pt][2][e], pmax[pt][3][e]));
            float sv = (j == 0) ? v.x : (j == 1) ? v.y : (j == 2) ? v.z : v.w;
            rel[e] = gg - sv;
        }
    }
    float* op = out + (size_t)b * CC * NN + n;
    for (int c = part * 16; c < part * 16 + 16; ++c) {
        const float4* w4 = (const float4*)(whs + c * FE);
        float s = 0.f;
        #pragma unroll
        for (int e0 = 0; e0 < 8; ++e0) {
            float4 w = w4[e0];
            s = fmaf(w.x, rel[e0 * 4 + 0], s);
            s = fmaf(w.y, rel[e0 * 4 + 1], s);
            s = fmaf(w.z, rel[e0 * 4 + 2], s);
            s = fmaf(w.w, rel[e0 * 4 + 3], s);
        }
        op[(size_t)c * NN] = s;
    }
}

extern "C" void kernel_launch(void* const* d_in, const int* in_sizes, int n_in,
                              void* d_out, int out_size, void* d_ws, size_t ws_size,
                              hipStream_t stream) {
    const float* xyz   = (const float*)d_in[0];
    const float* feat  = (const float*)d_in[1];
    const float* gamma = (const float*)d_in[2];
    const float* beta  = (const float*)d_in[3];
    const float* Wg    = (const float*)d_in[4];
    const float* Wh    = (const float*)d_in[5];
    float* out = (float*)d_out;
    (void)d_ws; (void)ws_size;

    hipLaunchKernelGGL(k_bnstats, dim3(512),  dim3(256),  0, stream, feat);
    hipLaunchKernelGGL(k_hist,    dim3(64),   dim3(1024), 0, stream, xyz);
    hipLaunchKernelGGL(k_scan,    dim3(8),    dim3(1024), 0, stream);
    hipLaunchKernelGGL(k_scatter, dim3(64),   dim3(1024), 0, stream, xyz);
    hipLaunchKernelGGL(k_feat0,   dim3(512),  dim3(256),  0, stream, feat, xyz, Wg, gamma, beta);
    hipLaunchKernelGGL(k_knn,     dim3(4096), dim3(256),  0, stream);
    hipLaunchKernelGGL(k_out,     dim3(1024), dim3(256),  0, stream, Wh, out);
}